// Round 1
// baseline (1900.564 us; speedup 1.0000x reference)
//
#include <hip/hip_runtime.h>
#include <math.h>

#define B_ 8
#define T_ 1000
#define F_ 96
#define C_ 16
#define D_ 64
#define EPS_ 1e-5f

__device__ __forceinline__ float gelu_erf(float v){
    return 0.5f*v*(1.0f+erff(v*0.70710678118654752440f));
}
__device__ __forceinline__ float sigmoidf(float v){
    return 1.0f/(1.0f+expf(-v));
}

// ---------------- Kernel A: conv_in -> x [B,T,F,C] ----------------
__global__ __launch_bounds__(128) void k_conv_in(
    const float* __restrict__ in, const float* __restrict__ g, const float* __restrict__ bb,
    const float* __restrict__ w_in, const float* __restrict__ b_in,
    float* __restrict__ x)
{
    int bt = blockIdx.x; int b = bt / T_; int t = bt % T_;
    int tid = threadIdx.x;
    __shared__ float r0[128], r1[128], r2[128], r3[128];
    float i0=0.f, i1=0.f;
    size_t base0 = ((size_t)(b*2+0)*T_ + t)*F_;
    size_t base1 = ((size_t)(b*2+1)*T_ + t)*F_;
    if (tid < F_){ i0 = in[base0+tid]; i1 = in[base1+tid]; }
    r0[tid]=i0; r1[tid]=i0*i0; r2[tid]=i1; r3[tid]=i1*i1;
    __syncthreads();
    for (int s=64; s>0; s>>=1){
        if (tid < s){ r0[tid]+=r0[tid+s]; r1[tid]+=r1[tid+s]; r2[tid]+=r2[tid+s]; r3[tid]+=r3[tid+s]; }
        __syncthreads();
    }
    float m0 = r0[0]*(1.f/F_), m1 = r2[0]*(1.f/F_);
    float ri0 = rsqrtf(r1[0]*(1.f/F_) - m0*m0 + EPS_);
    float ri1 = rsqrtf(r3[0]*(1.f/F_) - m1*m1 + EPS_);
    if (tid < F_){
        float gg = g[tid], b0 = bb[tid];
        float y0 = (i0-m0)*ri0*gg + b0;
        float y1 = (i1-m1)*ri1*gg + b0;
        float xv[16];
        #pragma unroll
        for (int c=0;c<C_;++c){
            xv[c] = gelu_erf(w_in[c*2+0]*y0 + w_in[c*2+1]*y1 + b_in[c]);
        }
        float4* xp = (float4*)(x + (((size_t)b*T_+t)*F_ + tid)*C_);
        xp[0] = make_float4(xv[0],xv[1],xv[2],xv[3]);
        xp[1] = make_float4(xv[4],xv[5],xv[6],xv[7]);
        xp[2] = make_float4(xv[8],xv[9],xv[10],xv[11]);
        xp[3] = make_float4(xv[12],xv[13],xv[14],xv[15]);
    }
}

// ---------------- Kernel B: ConvGRU scan -> hs [B,T,F,C], h_last -> d_out tail ----------------
// 192 blocks x 64 threads. Block = (b, 4 f-columns). thread: col = tid&3, c = tid>>2.
__global__ __launch_bounds__(64) void k_gru(
    const float* __restrict__ x, const float* __restrict__ wx, const float* __restrict__ wh,
    float* __restrict__ hs, float* __restrict__ d_out)
{
    int blk = blockIdx.x;
    int b = blk / 24; int f0 = (blk % 24) * 4;
    int tid = threadIdx.x;
    int col = tid & 3; int c = tid >> 2;
    __shared__ __align__(16) float xbuf[4*20];
    __shared__ __align__(16) float hbuf[4*20];
    float wxz[16], wxr[16], wxn[16], whz[16], whr[16], whn[16];
    #pragma unroll
    for (int k=0;k<16;++k){
        wxz[k] = wx[(c)*16+k];    wxr[k] = wx[(16+c)*16+k]; wxn[k] = wx[(32+c)*16+k];
        whz[k] = wh[(c)*16+k];    whr[k] = wh[(16+c)*16+k]; whn[k] = wh[(32+c)*16+k];
    }
    size_t xbase = ((size_t)b*T_*F_ + f0)*C_;
    float hval = 0.f;
    float xv = x[xbase + tid];
    for (int t=0;t<T_;++t){
        xbuf[(tid>>4)*20 + (tid&15)] = xv;
        hbuf[col*20 + c] = hval;
        __syncthreads();
        if (t+1 < T_) xv = x[xbase + (size_t)(t+1)*(F_*C_) + tid];
        float xr[16], hr[16];
        const float4* xp = (const float4*)(xbuf + col*20);
        const float4* hp = (const float4*)(hbuf + col*20);
        #pragma unroll
        for (int q=0;q<4;++q){
            float4 a = xp[q];  xr[4*q]=a.x; xr[4*q+1]=a.y; xr[4*q+2]=a.z; xr[4*q+3]=a.w;
            float4 h4 = hp[q]; hr[4*q]=h4.x; hr[4*q+1]=h4.y; hr[4*q+2]=h4.z; hr[4*q+3]=h4.w;
        }
        float zx=0.f,rx=0.f,nx=0.f,zh=0.f,rh=0.f,nh=0.f;
        #pragma unroll
        for (int k=0;k<16;++k){
            zx += wxz[k]*xr[k]; rx += wxr[k]*xr[k]; nx += wxn[k]*xr[k];
            zh += whz[k]*hr[k]; rh += whr[k]*hr[k]; nh += whn[k]*hr[k];
        }
        float z = sigmoidf(zx+zh);
        float r = sigmoidf(rx+rh);
        float n = tanhf(nx + r*nh);
        hval = (1.f-z)*n + z*hval;
        hs[xbase + (size_t)t*(F_*C_) + col*C_ + c] = hval;
        __syncthreads();
    }
    d_out[(size_t)B_*2*T_*F_ + ((size_t)b*C_ + c)*F_ + f0 + col] = hval;
}

// ---------------- Kernel C: fused attention + MLP + conv_out ----------------
__device__ __forceinline__ void ln_stats(const float* buf, float* mea, float* rstd, int tid){
    int row = tid >> 4, j = tid & 15;
    float s=0.f, q=0.f;
    #pragma unroll
    for (int i=0;i<6;++i){
        float v = buf[row*97 + j + 16*i];
        s += v; q += v*v;
    }
    #pragma unroll
    for (int off=8; off; off>>=1){
        s += __shfl_down(s, off, 16);
        q += __shfl_down(q, off, 16);
    }
    if (j==0){
        float m = s*(1.f/96.f);
        mea[row] = m;
        rstd[row] = rsqrtf(q*(1.f/96.f) - m*m + EPS_);
    }
}

__global__ __launch_bounds__(256) void k_tail(
    const float* __restrict__ x, const float* __restrict__ hs, const float* __restrict__ input,
    const float* __restrict__ ln_att_g, const float* __restrict__ ln_att_b,
    const float* __restrict__ wq, const float* __restrict__ bq,
    const float* __restrict__ wk, const float* __restrict__ bk,
    const float* __restrict__ wv, const float* __restrict__ bv,
    const float* __restrict__ wo, const float* __restrict__ bo,
    const float* __restrict__ ln_m_g, const float* __restrict__ ln_m_b,
    const float* __restrict__ wm1, const float* __restrict__ bm1,
    const float* __restrict__ wm2, const float* __restrict__ bm2,
    const float* __restrict__ ln_o_g, const float* __restrict__ ln_o_b,
    const float* __restrict__ w_out, const float* __restrict__ b_out,
    float* __restrict__ out)
{
    int bt = blockIdx.x; int b = bt / T_; int t = bt % T_;
    int tid = threadIdx.x;
    __shared__ float x2[16*97];      // holds x+hs, then ynorm_att, then x3, then x4
    __shared__ float vbuf[6240];     // v[96][65]; later o[96][65]; later ynorm_m + y1
    __shared__ float klb[24*65];
    __shared__ float vlb[24*65];
    __shared__ float kloc[4*65];
    __shared__ float qbuf[4*64];
    __shared__ float arow[4*28];
    __shared__ float wqT[16*65], wkT[16*65], wvT[16*65];
    __shared__ float woT[64*17];
    __shared__ float ymean[16*25];
    __shared__ float mea[16], rstd_[16];

    size_t xbase = ((size_t)b*T_ + t)*(size_t)(F_*C_);

    // P0: load x2 = x + hs (coalesced; c fastest) ; transpose weights into LDS
    for (int idx=tid; idx<1536; idx+=256){
        int c = idx & 15, f = idx >> 4;
        x2[c*97+f] = x[xbase+idx] + hs[xbase+idx];
    }
    for (int idx=tid; idx<1024; idx+=256){
        int c = idx & 15, d = idx >> 4;
        wqT[c*65+d] = wq[idx];
        wkT[c*65+d] = wk[idx];
        wvT[c*65+d] = wv[idx];
    }
    for (int idx=tid; idx<1024; idx+=256){
        int d = idx & 63, c = idx >> 6;
        woT[d*17+c] = wo[idx];
    }
    __syncthreads();

    // P1: attention LayerNorm stats
    ln_stats(x2, mea, rstd_, tid);
    __syncthreads();
    // P2: normalize in place (x2 now holds y)
    for (int idx=tid; idx<1536; idx+=256){
        int f = idx % 96, c = idx / 96;
        float v = x2[c*97+f];
        x2[c*97+f] = (v - mea[c])*rstd_[c]*ln_att_g[f] + ln_att_b[f];
    }
    __syncthreads();

    // P3: full v, and per-segment y means
    for (int idx=tid; idx<6144; idx+=256){
        int f = idx % 96, d = idx / 96;
        float acc = bv[d];
        #pragma unroll
        for (int c=0;c<16;++c) acc += wvT[c*65+d]*x2[c*97+f];
        vbuf[f*65+d] = acc;
    }
    for (int idx=tid; idx<384; idx+=256){
        int sm = idx % 24, c = idx / 24;
        ymean[c*25+sm] = 0.25f*(x2[c*97+4*sm]+x2[c*97+4*sm+1]+x2[c*97+4*sm+2]+x2[c*97+4*sm+3]);
    }
    __syncthreads();

    // P4: k_long, v_long (bias passes through the mean)
    for (int idx=tid; idx<3072; idx+=256){
        int sm = idx % 24, d = (idx/24) & 63;
        if (idx < 1536){
            float acc = bk[d];
            #pragma unroll
            for (int c=0;c<16;++c) acc += wkT[c*65+d]*ymean[c*25+sm];
            klb[sm*65+d] = acc;
        } else {
            float acc = bv[d];
            #pragma unroll
            for (int c=0;c<16;++c) acc += wvT[c*65+d]*ymean[c*25+sm];
            vlb[sm*65+d] = acc;
        }
    }
    __syncthreads();

    // P5: per-segment attention; wave w handles query-row r=w of segment s
    int w = tid >> 6;
    int lane = tid & 63;
    for (int s=0; s<24; ++s){
        {   // local k row w of this segment
            int fk = 4*s + w;
            float acc = bk[lane];
            #pragma unroll
            for (int c=0;c<16;++c) acc += wkT[c*65+lane]*x2[c*97+fk];
            kloc[w*65+lane] = acc;
        }
        __syncthreads();
        int fq = 4*s + w;
        float qd = bq[lane];
        #pragma unroll
        for (int c=0;c<16;++c) qd += wqT[c*65+lane]*x2[c*97+fq];
        qbuf[w*64+lane] = qd;
        __syncthreads();
        // scores: lane j over 28 keys (4 local | 24 long)
        float sc = -INFINITY;
        if (lane < 28){
            const float* key = (lane < 4) ? (kloc + lane*65) : (klb + (lane-4)*65);
            float acc = 0.f;
            #pragma unroll
            for (int d=0; d<64; ++d) acc += qbuf[w*64+d]*key[d];
            sc = acc * 0.125f;
        }
        float mx = sc;
        #pragma unroll
        for (int off=16; off; off>>=1) mx = fmaxf(mx, __shfl_xor(mx, off, 32));
        float p = (lane < 28) ? expf(sc - mx) : 0.f;
        float sum = p;
        #pragma unroll
        for (int off=16; off; off>>=1) sum += __shfl_xor(sum, off, 32);
        if (lane < 28) arow[w*28+lane] = p / sum;
        __syncthreads();
        // o: lane = d
        float od = 0.f;
        #pragma unroll
        for (int j=0;j<4;++j) od += arow[w*28+j]*vbuf[(4*s+j)*65+lane];
        #pragma unroll
        for (int m=0;m<24;++m) od += arow[w*28+4+m]*vlb[m*65+lane];
        __syncthreads();                 // all waves done reading v rows of this segment
        vbuf[(4*s+w)*65+lane] = od;      // overwrite v row with o row
        __syncthreads();
    }

    // P6: out-proj + residual (x2 becomes x3)
    for (int idx=tid; idx<1536; idx+=256){
        int c = idx & 15, f = idx >> 4;
        float acc = bo[c];
        #pragma unroll
        for (int d=0; d<64; ++d) acc += woT[d*17+c]*vbuf[f*65+d];
        x2[c*97+f] = (x[xbase + f*16 + c] + hs[xbase + f*16 + c]) + acc;
    }
    __syncthreads();

    // P7: MLP
    ln_stats(x2, mea, rstd_, tid);
    __syncthreads();
    for (int idx=tid; idx<1536; idx+=256){
        int f = idx % 96, c = idx / 96;
        vbuf[c*97+f] = (x2[c*97+f]-mea[c])*rstd_[c]*ln_m_g[f] + ln_m_b[f];
    }
    __syncthreads();
    for (int idx=tid; idx<1536; idx+=256){
        int f = idx % 96, c2 = idx / 96;
        float acc = bm1[c2];
        #pragma unroll
        for (int c=0;c<16;++c) acc += wm1[c2*16+c]*vbuf[c*97+f];
        vbuf[3200 + c2*97+f] = gelu_erf(acc);
    }
    __syncthreads();
    for (int idx=tid; idx<1536; idx+=256){
        int f = idx % 96, c = idx / 96;
        float acc = bm2[c];
        #pragma unroll
        for (int k=0;k<16;++k) acc += wm2[c*16+k]*vbuf[3200 + k*97+f];
        x2[c*97+f] += acc;
    }
    __syncthreads();

    // P8: conv_out + outer residual
    ln_stats(x2, mea, rstd_, tid);
    __syncthreads();
    if (tid < 192){
        int ch = tid / 96, f = tid % 96;
        float gg = ln_o_g[f], b2 = ln_o_b[f];
        float acc = b_out[ch];
        #pragma unroll
        for (int c=0;c<16;++c) acc += w_out[ch*16+c]*((x2[c*97+f]-mea[c])*rstd_[c]*gg + b2);
        size_t oidx = ((size_t)(b*2+ch)*T_ + t)*F_ + f;
        out[oidx] = input[oidx] + tanhf(acc);
    }
}

extern "C" void kernel_launch(void* const* d_in, const int* in_sizes, int n_in,
                              void* d_out, int out_size, void* d_ws, size_t ws_size,
                              hipStream_t stream)
{
    const float* input   = (const float*)d_in[0];
    const float* ln_in_g = (const float*)d_in[1];
    const float* ln_in_b = (const float*)d_in[2];
    const float* w_in    = (const float*)d_in[3];
    const float* b_in    = (const float*)d_in[4];
    const float* gru_wx  = (const float*)d_in[5];
    const float* gru_wh  = (const float*)d_in[6];
    const float* ln_att_g= (const float*)d_in[7];
    const float* ln_att_b= (const float*)d_in[8];
    const float* wq = (const float*)d_in[9];
    const float* bq = (const float*)d_in[10];
    const float* wk = (const float*)d_in[11];
    const float* bk = (const float*)d_in[12];
    const float* wv = (const float*)d_in[13];
    const float* bv = (const float*)d_in[14];
    const float* wo = (const float*)d_in[15];
    const float* bo = (const float*)d_in[16];
    const float* ln_m_g = (const float*)d_in[17];
    const float* ln_m_b = (const float*)d_in[18];
    const float* w_m1 = (const float*)d_in[19];
    const float* b_m1 = (const float*)d_in[20];
    const float* w_m2 = (const float*)d_in[21];
    const float* b_m2 = (const float*)d_in[22];
    const float* ln_out_g = (const float*)d_in[23];
    const float* ln_out_b = (const float*)d_in[24];
    const float* w_out = (const float*)d_in[25];
    const float* b_out = (const float*)d_in[26];
    float* out = (float*)d_out;

    float* x  = (float*)d_ws;                       // [B,T,F,C]
    float* hs = x + (size_t)B_*T_*F_*C_;            // [B,T,F,C]

    k_conv_in<<<B_*T_, 128, 0, stream>>>(input, ln_in_g, ln_in_b, w_in, b_in, x);
    k_gru<<<192, 64, 0, stream>>>(x, gru_wx, gru_wh, hs, out);
    k_tail<<<B_*T_, 256, 0, stream>>>(x, hs, input, ln_att_g, ln_att_b,
        wq, bq, wk, bk, wv, bv, wo, bo, ln_m_g, ln_m_b, w_m1, b_m1, w_m2, b_m2,
        ln_out_g, ln_out_b, w_out, b_out, out);
}